// Round 6
// baseline (197.465 us; speedup 1.0000x reference)
//
#include <hip/hip_runtime.h>

// out[b,s,h] = sum_{a,d} x[b,a,h,d] * K[s,a] * W[s,d]
// bf16 GEMM: out[(b,h), s] = X[(b,h),(a,d)] . Wm[s,(a,d)]^T
//   M = B*H = 196608, K = 112 -> padded 128 (exact zeros), N = S = 512
//
// Round-6: PERSISTENT blocks + double-buffered A staging.
//  - grid = 512 blocks (exactly 2/CU), each owns 4 consecutive 32-batch chunks.
//  - per generation g: prefetch chunk g+1's x into REGISTERS during chunk g's
//    compute+store, then cvt->ds_write into A-buffer (g+1)&1; ONE barrier/gen.
//    => store stream never pauses for cold x reads.
//  - staging addresses precomputed once (generation-invariant).
//  - wave tile 48m x 32s; B frags direct from global (L2-hot).
//  - epilogue: two 16-spot halves through 3KB wave-private LDS -> coalesced
//    float4 stores (192B-aligned full-line runs).
//  LDS = 2x24KB (A dbuf) + 8x3KB (ep) = 72KB -> 2 blocks/CU.

#define A_DIM 14
#define H_DIM 3
#define D_DIM 8
#define S_DIM 512
#define KP    128
#define XSTR  (A_DIM * H_DIM * D_DIM)   // 336 floats per batch
#define OSTR  (S_DIM * H_DIM)           // 1536 floats per batch

#define BB 32                  // batches per chunk
#define BM 96                  // m rows per chunk
#define BN 128                 // spots per s-block
#define CPB 4                  // chunks per block (2048 chunks / 512 blocks)
#define A_LDS1 24576           // one A buffer: 96 rows * 256 B
#define EP_OFF (2 * A_LDS1)    // 49152
#define EP_CHUNK 3072          // per-wave: 16 batches * 16 s * 3 h * 4 B
#define LDS_BYTES (EP_OFF + 8 * EP_CHUNK)   // 73728

typedef short bf16x8 __attribute__((ext_vector_type(8)));
typedef float f32x4  __attribute__((ext_vector_type(4)));

static __device__ __forceinline__ unsigned f2bf(float f) {
    unsigned u = __float_as_uint(f);
    u += 0x7FFFu + ((u >> 16) & 1u);
    return u >> 16;
}

// ---------- build Wm[s][k] bf16, k = a*8+d, zero-padded to KP ----------
__global__ __launch_bounds__(S_DIM) void build_wm_kernel(
    const float* __restrict__ windWeights,   // (S, D)
    const float* __restrict__ alt,           // (S, 1)
    unsigned short* __restrict__ wmg)        // (S, KP) bf16 bits
{
    const int s = threadIdx.x;
    const float av = alt[s];
    float w[D_DIM];
#pragma unroll
    for (int d = 0; d < D_DIM; ++d) w[d] = windWeights[s * D_DIM + d];
#pragma unroll
    for (int a = 0; a < A_DIM; ++a) {
        const float g  = (float)a - av;
        const float t1 = fminf(fmaxf(g + 1.0f, 0.0f), 1.0f);
        const float t0 = fminf(fmaxf(g,        0.0f), 1.0f);
        const float Ka = t1 - t0;   // exact reference clip form
#pragma unroll
        for (int d = 0; d < D_DIM; ++d)
            wmg[s * KP + a * D_DIM + d] = (unsigned short)f2bf(Ka * w[d]);
    }
#pragma unroll
    for (int k = A_DIM * D_DIM; k < KP; ++k) wmg[s * KP + k] = 0;
}

// ---------- main GEMM ----------
__global__ __launch_bounds__(512, 4) void wind_gemm_kernel(
    const float* __restrict__ x,             // (B, A, H, D) fp32
    const unsigned short* __restrict__ wmg,  // (S, KP) bf16
    float* __restrict__ out)                 // (B, S, H) fp32
{
    __shared__ __align__(16) char lds[LDS_BYTES];

    const int tid = threadIdx.x;

    // ---- precompute staging addresses (generation-invariant) ----
    // 84 float4 per batch, 2688 per chunk; thread handles q = tid + it*512.
    // it=5 is valid only for tid<128: clamp to the thread's it=0 slot
    // (duplicate load+write of identical data -> harmless).
    int offb[6];   // float offset within chunk
    int bytb[6];   // swizzled LDS byte offset within A buffer
#pragma unroll
    for (int it = 0; it < 6; ++it) {
        int q = tid + it * 512;
        if (q >= 84 * BB) q = tid;
        const int b_loc = q / 84;
        const int o   = q - b_loc * 84;
        const int of  = o * 4;
        const int a   = of / 24;
        const int r24 = of - a * 24;
        const int h   = r24 >> 3;
        const int d0  = r24 & 7;
        const int m   = b_loc * 3 + h;
        int byte = m * 256 + a * 16 + d0 * 2;
        byte ^= (m & 7) << 4;
        offb[it] = b_loc * XSTR + of;
        bytb[it] = byte;
    }

    // ---- prologue: load chunk 0, write zero-pads for BOTH buffers ----
    const size_t chunk0 = (size_t)blockIdx.x * CPB;
    float4 rx[6];
    {
        const float* xc = x + chunk0 * (BB * XSTR);
#pragma unroll
        for (int it = 0; it < 6; ++it)
            rx[it] = *reinterpret_cast<const float4*>(xc + offb[it]);
    }
#pragma unroll
    for (int e = 0; e < 2; ++e) {
        const int p = tid + e * 512;
        if (p < BM * 4 * 2) {                 // 768 pad writes (2 buffers)
            const int bufsel = p >= BM * 4;
            const int pp = p - bufsel * BM * 4;
            const int m = pp >> 2, cc = pp & 3;
            int byte = m * 256 + 224 + cc * 8;
            byte ^= (m & 7) << 4;
            *reinterpret_cast<uint2*>(lds + bufsel * A_LDS1 + byte) = make_uint2(0u, 0u);
        }
    }
#pragma unroll
    for (int it = 0; it < 6; ++it) {
        const float4 v = rx[it];
        const unsigned lo = f2bf(v.x) | (f2bf(v.y) << 16);
        const unsigned hi = f2bf(v.z) | (f2bf(v.w) << 16);
        *reinterpret_cast<uint2*>(lds + bytb[it]) = make_uint2(lo, hi);
    }
    __syncthreads();

    // ---- wave decomposition: 8 waves = 2 m x 4 s; wave tile 48m x 32s ----
    const int lane = tid & 63;
    const int wid  = tid >> 6;
    const int wm_  = wid >> 2;           // 0..1
    const int ws_  = wid & 3;            // 0..3
    const int r    = lane & 15;
    const int kq   = lane >> 4;          // 0..3
    const int swz  = (r & 7) << 4;
    const int r12  = r * 12;

    const int abase0 = (wm_ * 48 + r) * 256 + kq * 16;
    char* ep = lds + EP_OFF + wid * EP_CHUNK;

#pragma unroll 1
    for (int g = 0; g < CPB; ++g) {
        const size_t b0c = (chunk0 + g) * BB;

        // prefetch next chunk's x into registers (hidden under this chunk's work)
        if (g + 1 < CPB) {
            const float* xc = x + (b0c + BB) * XSTR;
#pragma unroll
            for (int it = 0; it < 6; ++it)
                rx[it] = *reinterpret_cast<const float4*>(xc + offb[it]);
        }

        const int abuf = (g & 1) * A_LDS1;

#pragma unroll 1
        for (int k = 0; k < 4; ++k) {
            const int sblk = (k + wid + g) & 3;   // per-wave stagger
            const int s0 = sblk * BN;

            // B frags direct from global (L2-hot)
            const char* wb = (const char*)wmg + (size_t)(s0 + ws_ * 32 + r) * 256 + kq * 16;
            bf16x8 bfr[4][2];
#pragma unroll
            for (int ks = 0; ks < 4; ++ks)
#pragma unroll
                for (int j = 0; j < 2; ++j)
                    bfr[ks][j] = *reinterpret_cast<const bf16x8*>(wb + j * 16 * 256 + ks * 64);

            f32x4 acc[3][2];
#pragma unroll
            for (int i = 0; i < 3; ++i)
#pragma unroll
                for (int j = 0; j < 2; ++j) {
                    f32x4 z = {0.f, 0.f, 0.f, 0.f};
                    acc[i][j] = z;
                }

#pragma unroll
            for (int ks = 0; ks < 4; ++ks) {
                bf16x8 af[3];
#pragma unroll
                for (int i = 0; i < 3; ++i)
                    af[i] = *reinterpret_cast<bf16x8*>(lds + abuf + ((abase0 + i * 16 * 256 + ks * 64) ^ swz));
#pragma unroll
                for (int i = 0; i < 3; ++i)
#pragma unroll
                    for (int j = 0; j < 2; ++j)
                        acc[i][j] = __builtin_amdgcn_mfma_f32_16x16x32_bf16(af[i], bfr[ks][j], acc[i][j], 0, 0, 0);
            }

            // ---- epilogue: two 16-spot halves through 3KB wave-private LDS ----
            // half layout: [b_in(16)][s(16)][h(3)] floats = b_in*192 + s*12 + h*4
#pragma unroll
            for (int jj = 0; jj < 2; ++jj) {
#pragma unroll
                for (int i = 0; i < 3; ++i) {
                    const int m0 = i * 16 + kq * 4;
                    int b_in = (unsigned)m0 / 3u;
                    int h    = m0 - b_in * 3;
#pragma unroll
                    for (int reg = 0; reg < 4; ++reg) {
                        *reinterpret_cast<float*>(ep + b_in * 192 + h * 4 + r12) = acc[i][jj][reg];
                        ++h;
                        if (h == 3) { h = 0; ++b_in; }
                    }
                }
                asm volatile("s_waitcnt lgkmcnt(0)" ::: "memory");

                const size_t obase = (size_t)(b0c + wm_ * 16) * OSTR
                                   + (size_t)(s0 + ws_ * 32 + jj * 16) * 3;
#pragma unroll
                for (int t = 0; t < 3; ++t) {
                    const unsigned u    = (unsigned)lane + t * 64u;   // < 192
                    const unsigned b_in = u / 12u;                    // 12 float4/batch-run
                    const unsigned rem  = u - b_in * 12u;
                    const float4 v = *reinterpret_cast<const float4*>(ep + u * 16u);
                    *reinterpret_cast<float4*>(out + obase + (size_t)b_in * OSTR + rem * 4u) = v;
                }
                asm volatile("" ::: "memory");
            }
        }

        // write prefetched chunk into the other A buffer, one barrier per gen
        if (g + 1 < CPB) {
            char* ab = lds + ((g + 1) & 1) * A_LDS1;
#pragma unroll
            for (int it = 0; it < 6; ++it) {
                const float4 v = rx[it];
                const unsigned lo = f2bf(v.x) | (f2bf(v.y) << 16);
                const unsigned hi = f2bf(v.z) | (f2bf(v.w) << 16);
                *reinterpret_cast<uint2*>(ab + bytb[it]) = make_uint2(lo, hi);
            }
        }
        __syncthreads();
    }
}

extern "C" void kernel_launch(void* const* d_in, const int* in_sizes, int n_in,
                              void* d_out, int out_size, void* d_ws, size_t ws_size,
                              hipStream_t stream) {
    const float* x           = (const float*)d_in[0];
    const float* windWeights = (const float*)d_in[1];
    const float* alt         = (const float*)d_in[2];
    float* out = (float*)d_out;

    const int Btot = in_sizes[0] / XSTR;     // 65536

    unsigned short* wmg = (unsigned short*)d_ws;   // S_DIM * KP * 2 = 128 KB

    build_wm_kernel<<<1, S_DIM, 0, stream>>>(windWeights, alt, wmg);

    const int blocks = Btot / (BB * CPB);          // 512
    wind_gemm_kernel<<<blocks, 512, 0, stream>>>(x, wmg, out);
}

// Round 8
// 135.580 us; speedup vs baseline: 1.4564x; 1.4564x over previous
//
#include <hip/hip_runtime.h>

// out[b,s,h] = sum_{a,d} x[b,a,h,d] * K[s,a] * W[s,d]
// bf16 GEMM: out[(b,h), s] = X[(b,h),(a,d)] . Wm[s,(a,d)]^T
//   M = B*H = 196608, K = 112 -> padded 128 (exact zeros), N = S = 512
//
// Round-8 = round-5 (124.8us, passed) + A-fragment hoist ONLY:
//  - 12 ds_read_b128 A-frags read ONCE per chunk (sblk-invariant), was x4.
//  - B frags ks-level double-buffered in regs (16 regs) to stay <=128 VGPR.
//  - epilogue identical to round 5: C++ pair stores 192B apart (compiler
//    fuses to ds_write2_b32), wave-private 6KB chunk, coalesced float4 out.
//  - round-7's inline-asm ds_write2 REMOVED (generic-pointer low-32 is NOT an
//    LDS offset -> wrote wrong LDS locations, absmax 14.6).
//  LDS = 24KB (A) + 48KB (ep) = 72KB -> 2 blocks/CU.

#define A_DIM 14
#define H_DIM 3
#define D_DIM 8
#define S_DIM 512
#define KP    128
#define XSTR  (A_DIM * H_DIM * D_DIM)   // 336 floats per batch
#define OSTR  (S_DIM * H_DIM)           // 1536 floats per batch

#define BB 32                 // batches per block
#define BM 96                 // m rows per block
#define BN 128                // spots per s-block
#define A_LDS (BM * 256)      // 24576 B
#define EP_CHUNK 6144         // per-wave: 16 batches * 32 s * 3 h * 4B
#define LDS_BYTES (A_LDS + 8 * EP_CHUNK)   // 73728 B

typedef short bf16x8 __attribute__((ext_vector_type(8)));
typedef float f32x4  __attribute__((ext_vector_type(4)));

static __device__ __forceinline__ unsigned f2bf(float f) {
    unsigned u = __float_as_uint(f);
    u += 0x7FFFu + ((u >> 16) & 1u);
    return u >> 16;
}

// ---------- build Wm[s][k] bf16, k = a*8+d, zero-padded to KP ----------
__global__ __launch_bounds__(S_DIM) void build_wm_kernel(
    const float* __restrict__ windWeights,   // (S, D)
    const float* __restrict__ alt,           // (S, 1)
    unsigned short* __restrict__ wmg)        // (S, KP) bf16 bits
{
    const int s = threadIdx.x;
    const float av = alt[s];
    float w[D_DIM];
#pragma unroll
    for (int d = 0; d < D_DIM; ++d) w[d] = windWeights[s * D_DIM + d];
#pragma unroll
    for (int a = 0; a < A_DIM; ++a) {
        const float g  = (float)a - av;
        const float t1 = fminf(fmaxf(g + 1.0f, 0.0f), 1.0f);
        const float t0 = fminf(fmaxf(g,        0.0f), 1.0f);
        const float Ka = t1 - t0;   // exact reference clip form
#pragma unroll
        for (int d = 0; d < D_DIM; ++d)
            wmg[s * KP + a * D_DIM + d] = (unsigned short)f2bf(Ka * w[d]);
    }
#pragma unroll
    for (int k = A_DIM * D_DIM; k < KP; ++k) wmg[s * KP + k] = 0;
}

// ---------- main GEMM ----------
__global__ __launch_bounds__(512, 4) void wind_gemm_kernel(
    const float* __restrict__ x,             // (B, A, H, D) fp32
    const unsigned short* __restrict__ wmg,  // (S, KP) bf16
    float* __restrict__ out)                 // (B, S, H) fp32
{
    __shared__ __align__(16) char lds[LDS_BYTES];

    const int tid = threadIdx.x;
    const int b0  = blockIdx.x * BB;

    // ---- stage A: x[b0..b0+31] fp32 -> bf16 LDS [m=96][256B], swizzled ----
    const float* xg = x + (size_t)b0 * XSTR;
#pragma unroll
    for (int it = 0; it < 6; ++it) {
        const int q = tid + it * 512;          // float4 id; 84 per batch, 2688 total
        if (q < 84 * BB) {
            const int b_loc = q / 84;
            const int o   = q - b_loc * 84;
            const int of  = o * 4;             // float offset within batch
            const int a   = of / 24;
            const int r24 = of - a * 24;
            const int h   = r24 >> 3;
            const int d0  = r24 & 7;           // 0 or 4
            const float4 v = *reinterpret_cast<const float4*>(xg + (size_t)b_loc * XSTR + of);
            const unsigned lo = f2bf(v.x) | (f2bf(v.y) << 16);
            const unsigned hi = f2bf(v.z) | (f2bf(v.w) << 16);
            const int m = b_loc * 3 + h;
            int byte = m * 256 + a * 16 + d0 * 2;
            byte ^= (m & 7) << 4;
            *reinterpret_cast<uint2*>(lds + byte) = make_uint2(lo, hi);
        }
    }
    // zero-pad k = 112..127 (32 B per row as 4 x uint2; 384 writes)
    if (tid < BM * 4) {
        const int m = tid >> 2;
        const int c = tid & 3;
        int byte = m * 256 + 224 + c * 8;
        byte ^= (m & 7) << 4;
        *reinterpret_cast<uint2*>(lds + byte) = make_uint2(0u, 0u);
    }
    __syncthreads();

    // ---- wave decomposition: 8 waves = 2 m x 4 s; wave tile 48m x 32s ----
    const int lane = tid & 63;
    const int wid  = tid >> 6;
    const int wm_  = wid >> 2;           // 0..1
    const int ws_  = wid & 3;            // 0..3
    const int r    = lane & 15;
    const int kq   = lane >> 4;          // 0..3
    const int swz  = (r & 7) << 4;
    const int r12  = r * 12;

    const int abase = (wm_ * 48 + r) * 256 + kq * 16;
    char* ep = lds + A_LDS + wid * EP_CHUNK;

    // ---- hoist A fragments: 12 ds_read_b128, once per chunk ----
    bf16x8 af[4][3];
#pragma unroll
    for (int ks = 0; ks < 4; ++ks)
#pragma unroll
        for (int i = 0; i < 3; ++i)
            af[ks][i] = *reinterpret_cast<bf16x8*>(lds + ((abase + i * 16 * 256 + ks * 64) ^ swz));

#pragma unroll 1
    for (int k = 0; k < 4; ++k) {
        const int sblk = (k + wid + blockIdx.x) & 3;   // per-wave stagger
        const int s0 = sblk * BN;

        // B frags: ks-level register double-buffer (L2-hot global reads)
        const char* wb = (const char*)wmg + (size_t)(s0 + ws_ * 32 + r) * 256 + kq * 16;
        bf16x8 bca = *reinterpret_cast<const bf16x8*>(wb);
        bf16x8 bcb = *reinterpret_cast<const bf16x8*>(wb + 16 * 256);

        f32x4 acc[3][2];
#pragma unroll
        for (int i = 0; i < 3; ++i)
#pragma unroll
            for (int j = 0; j < 2; ++j) {
                f32x4 z = {0.f, 0.f, 0.f, 0.f};
                acc[i][j] = z;
            }

#pragma unroll
        for (int ks = 0; ks < 4; ++ks) {
            bf16x8 bna, bnb;
            if (ks < 3) {
                bna = *reinterpret_cast<const bf16x8*>(wb + (ks + 1) * 64);
                bnb = *reinterpret_cast<const bf16x8*>(wb + 16 * 256 + (ks + 1) * 64);
            }
#pragma unroll
            for (int i = 0; i < 3; ++i) {
                acc[i][0] = __builtin_amdgcn_mfma_f32_16x16x32_bf16(af[ks][i], bca, acc[i][0], 0, 0, 0);
                acc[i][1] = __builtin_amdgcn_mfma_f32_16x16x32_bf16(af[ks][i], bcb, acc[i][1], 0, 0, 0);
            }
            if (ks < 3) { bca = bna; bcb = bnb; }
        }

        // ---- epilogue: acc -> wave-private LDS chunk in out-layout ----
        // chunk layout: [b_in(16)][soff(32)][h(3)] floats; addr = b_in*384 + soff*12 + h*4
        // j=0 at soff=r, j=1 at soff=r+16 (+192B) -> compiler fuses to ds_write2
#pragma unroll
        for (int i = 0; i < 3; ++i) {
            const int m_in0 = i * 16 + kq * 4;   // m within wave tile (48 rows)
            int b_in = (unsigned)m_in0 / 3u;
            int h    = m_in0 - b_in * 3;
#pragma unroll
            for (int reg = 0; reg < 4; ++reg) {
                const int bh = b_in * 384 + h * 4;
                *reinterpret_cast<float*>(ep + bh + r12)       = acc[i][0][reg];
                *reinterpret_cast<float*>(ep + bh + r12 + 192) = acc[i][1][reg];
                ++h;
                if (h == 3) { h = 0; ++b_in; }
            }
        }
        asm volatile("s_waitcnt lgkmcnt(0)" ::: "memory");

        // ---- readback + fully coalesced float4 stores ----
        const size_t obase = (size_t)(b0 + wm_ * 16) * OSTR + (size_t)(s0 + ws_ * 32) * 3;
#pragma unroll
        for (int t = 0; t < 6; ++t) {
            const unsigned u    = (unsigned)lane + t * 64u;  // float4 index, < 384
            const unsigned b_in = u / 24u;                   // 24 float4 per batch
            const unsigned rem  = u - b_in * 24u;
            const float4 v = *reinterpret_cast<const float4*>(ep + u * 16u);
            *reinterpret_cast<float4*>(out + obase + (size_t)b_in * OSTR + rem * 4u) = v;
        }
        asm volatile("" ::: "memory");   // keep next sblk's LDS writes after these reads
    }
}

extern "C" void kernel_launch(void* const* d_in, const int* in_sizes, int n_in,
                              void* d_out, int out_size, void* d_ws, size_t ws_size,
                              hipStream_t stream) {
    const float* x           = (const float*)d_in[0];
    const float* windWeights = (const float*)d_in[1];
    const float* alt         = (const float*)d_in[2];
    float* out = (float*)d_out;

    const int Btot = in_sizes[0] / XSTR;     // 65536

    unsigned short* wmg = (unsigned short*)d_ws;   // S_DIM * KP * 2 = 128 KB

    build_wm_kernel<<<1, S_DIM, 0, stream>>>(windWeights, alt, wmg);

    const int blocks = Btot / BB;                  // 2048
    wind_gemm_kernel<<<blocks, 512, 0, stream>>>(x, wmg, out);
}

// Round 9
// 130.085 us; speedup vs baseline: 1.5180x; 1.0422x over previous
//
#include <hip/hip_runtime.h>

// out[b,s,h] = sum_{a,d} x[b,a,h,d] * K[s,a] * W[s,d]
// bf16 GEMM: out[(b,h), s] = X[(b,h),(a,d)] . Wm[s,(a,d)]^T
//   M = B*H = 196608, K = 112 -> padded 128 (exact zeros), N = S = 512
//
// Round-9 = round-5 core + BLOCK-POOLED LINE-ALIGNED epilogue:
//  - ep buffer is block-shared 48KB in exact out-layout:
//    [32 batches][128 spots][3 h] = 32 contiguous 1536B runs.
//  - all 8 waves deposit acc (ds_write2-fusable 192B pairs), raw s_barrier
//    (+lgkmcnt(0), no vmcnt drain), then block-cooperative store: every
//    wave-store = contiguous 1KB, 128B-aligned, FULL LINES ONLY.
//    (round-5's 384B/6KB-stride ragged stores cost ~2.5x the L2 write
//     requests per byte -> 3.2 vs 6.9 TB/s; this removes that.)
//  - stagger removed (pooling needs lockstep sblk); A-frags re-read per
//    sblk (round-8 showed hoisting them regresses).
//  LDS = 24KB (A) + 48KB (ep) = 72KB -> 2 blocks/CU.

#define A_DIM 14
#define H_DIM 3
#define D_DIM 8
#define S_DIM 512
#define KP    128
#define XSTR  (A_DIM * H_DIM * D_DIM)   // 336 floats per batch
#define OSTR  (S_DIM * H_DIM)           // 1536 floats per batch

#define BB 32                 // batches per block
#define BM 96                 // m rows per block
#define BN 128                // spots per s-block
#define A_LDS (BM * 256)      // 24576 B
#define EP_BYTES (BB * BN * H_DIM * 4)      // 49152 B
#define LDS_BYTES (A_LDS + EP_BYTES)        // 73728 B

typedef short bf16x8 __attribute__((ext_vector_type(8)));
typedef float f32x4  __attribute__((ext_vector_type(4)));

static __device__ __forceinline__ unsigned f2bf(float f) {
    unsigned u = __float_as_uint(f);
    u += 0x7FFFu + ((u >> 16) & 1u);
    return u >> 16;
}

// ---------- build Wm[s][k] bf16, k = a*8+d, zero-padded to KP ----------
__global__ __launch_bounds__(S_DIM) void build_wm_kernel(
    const float* __restrict__ windWeights,   // (S, D)
    const float* __restrict__ alt,           // (S, 1)
    unsigned short* __restrict__ wmg)        // (S, KP) bf16 bits
{
    const int s = threadIdx.x;
    const float av = alt[s];
    float w[D_DIM];
#pragma unroll
    for (int d = 0; d < D_DIM; ++d) w[d] = windWeights[s * D_DIM + d];
#pragma unroll
    for (int a = 0; a < A_DIM; ++a) {
        const float g  = (float)a - av;
        const float t1 = fminf(fmaxf(g + 1.0f, 0.0f), 1.0f);
        const float t0 = fminf(fmaxf(g,        0.0f), 1.0f);
        const float Ka = t1 - t0;   // exact reference clip form
#pragma unroll
        for (int d = 0; d < D_DIM; ++d)
            wmg[s * KP + a * D_DIM + d] = (unsigned short)f2bf(Ka * w[d]);
    }
#pragma unroll
    for (int k = A_DIM * D_DIM; k < KP; ++k) wmg[s * KP + k] = 0;
}

// ---------- main GEMM ----------
__global__ __launch_bounds__(512, 4) void wind_gemm_kernel(
    const float* __restrict__ x,             // (B, A, H, D) fp32
    const unsigned short* __restrict__ wmg,  // (S, KP) bf16
    float* __restrict__ out)                 // (B, S, H) fp32
{
    __shared__ __align__(16) char lds[LDS_BYTES];

    const int tid = threadIdx.x;
    const int b0  = blockIdx.x * BB;

    // ---- stage A: x[b0..b0+31] fp32 -> bf16 LDS [m=96][256B], swizzled ----
    const float* xg = x + (size_t)b0 * XSTR;
#pragma unroll
    for (int it = 0; it < 6; ++it) {
        const int q = tid + it * 512;          // float4 id; 84 per batch, 2688 total
        if (q < 84 * BB) {
            const int b_loc = q / 84;
            const int o   = q - b_loc * 84;
            const int of  = o * 4;             // float offset within batch
            const int a   = of / 24;
            const int r24 = of - a * 24;
            const int h   = r24 >> 3;
            const int d0  = r24 & 7;           // 0 or 4
            const float4 v = *reinterpret_cast<const float4*>(xg + (size_t)b_loc * XSTR + of);
            const unsigned lo = f2bf(v.x) | (f2bf(v.y) << 16);
            const unsigned hi = f2bf(v.z) | (f2bf(v.w) << 16);
            const int m = b_loc * 3 + h;
            int byte = m * 256 + a * 16 + d0 * 2;
            byte ^= (m & 7) << 4;
            *reinterpret_cast<uint2*>(lds + byte) = make_uint2(lo, hi);
        }
    }
    // zero-pad k = 112..127 (32 B per row as 4 x uint2; 384 writes)
    if (tid < BM * 4) {
        const int m = tid >> 2;
        const int c = tid & 3;
        int byte = m * 256 + 224 + c * 8;
        byte ^= (m & 7) << 4;
        *reinterpret_cast<uint2*>(lds + byte) = make_uint2(0u, 0u);
    }
    __syncthreads();

    // ---- wave decomposition: 8 waves = 2 m x 4 s; wave tile 48m x 32s ----
    const int lane = tid & 63;
    const int wid  = tid >> 6;
    const int wm_  = wid >> 2;           // 0..1
    const int ws_  = wid & 3;            // 0..3
    const int r    = lane & 15;
    const int kq   = lane >> 4;          // 0..3
    const int swz  = (r & 7) << 4;

    const int abase = (wm_ * 48 + r) * 256 + kq * 16;
    char* eplds = lds + A_LDS;
    char* epw   = eplds + (ws_ * 32 + r) * 12;   // this thread's j=0 column

#pragma unroll 1
    for (int sblk = 0; sblk < 4; ++sblk) {
        const int s0 = sblk * BN;

        // B frags direct from global (L2-hot)
        const char* wb = (const char*)wmg + (size_t)(s0 + ws_ * 32 + r) * 256 + kq * 16;
        bf16x8 bfr[4][2];
#pragma unroll
        for (int ks = 0; ks < 4; ++ks)
#pragma unroll
            for (int j = 0; j < 2; ++j)
                bfr[ks][j] = *reinterpret_cast<const bf16x8*>(wb + j * 16 * 256 + ks * 64);

        f32x4 acc[3][2];
#pragma unroll
        for (int i = 0; i < 3; ++i)
#pragma unroll
            for (int j = 0; j < 2; ++j) {
                f32x4 z = {0.f, 0.f, 0.f, 0.f};
                acc[i][j] = z;
            }

#pragma unroll
        for (int ks = 0; ks < 4; ++ks) {
            bf16x8 af[3];
#pragma unroll
            for (int i = 0; i < 3; ++i)
                af[i] = *reinterpret_cast<bf16x8*>(lds + ((abase + i * 16 * 256 + ks * 64) ^ swz));
#pragma unroll
            for (int i = 0; i < 3; ++i)
#pragma unroll
                for (int j = 0; j < 2; ++j)
                    acc[i][j] = __builtin_amdgcn_mfma_f32_16x16x32_bf16(af[i], bfr[ks][j], acc[i][j], 0, 0, 0);
        }

        // ---- deposit acc into block-shared ep buffer (exact out-layout) ----
        // ep layout: [b_in(32)][srel(128)][h(3)] floats; byte = b_in*1536 + srel*12 + h*4
        // j=0 at srel = ws*32+r, j=1 at +16 spots (+192 B) -> ds_write2-fusable
#pragma unroll
        for (int i = 0; i < 3; ++i) {
            const int m0 = wm_ * 48 + i * 16 + kq * 4;   // m within block tile
            int b_in = (unsigned)m0 / 3u;
            int h    = m0 - b_in * 3;
#pragma unroll
            for (int reg = 0; reg < 4; ++reg) {
                const int bh = b_in * 1536 + h * 4;
                *reinterpret_cast<float*>(epw + bh)       = acc[i][0][reg];
                *reinterpret_cast<float*>(epw + bh + 192) = acc[i][1][reg];
                ++h;
                if (h == 3) { h = 0; ++b_in; }
            }
        }
        asm volatile("s_waitcnt lgkmcnt(0)" ::: "memory");   // own ds_writes done
        __builtin_amdgcn_sched_barrier(0);
        __builtin_amdgcn_s_barrier();                        // all ep writes visible
        __builtin_amdgcn_sched_barrier(0);

        // ---- block-cooperative store: contiguous 1KB per wave-instr, full lines ----
        // region = 32 runs of 1536B at 6144B stride; run starts 128B-aligned.
        const size_t outbase = (size_t)b0 * OSTR + (size_t)s0 * 3;   // floats
#pragma unroll
        for (int t = 0; t < 6; ++t) {
            const unsigned u   = (unsigned)tid + t * 512u;   // float4 id, < 3072
            const unsigned run = u / 96u;                    // batch 0..31
            const unsigned rem = u - run * 96u;              // float4 within run
            const float4 v = *reinterpret_cast<const float4*>(eplds + u * 16u);
            *reinterpret_cast<float4*>(out + outbase + (size_t)run * OSTR + rem * 4u) = v;
        }
        __builtin_amdgcn_sched_barrier(0);
        __builtin_amdgcn_s_barrier();        // all ep reads done; safe to overwrite
        __builtin_amdgcn_sched_barrier(0);   // (stores stay in flight: no vmcnt drain)
    }
}

extern "C" void kernel_launch(void* const* d_in, const int* in_sizes, int n_in,
                              void* d_out, int out_size, void* d_ws, size_t ws_size,
                              hipStream_t stream) {
    const float* x           = (const float*)d_in[0];
    const float* windWeights = (const float*)d_in[1];
    const float* alt         = (const float*)d_in[2];
    float* out = (float*)d_out;

    const int Btot = in_sizes[0] / XSTR;     // 65536

    unsigned short* wmg = (unsigned short*)d_ws;   // S_DIM * KP * 2 = 128 KB

    build_wm_kernel<<<1, S_DIM, 0, stream>>>(windWeights, alt, wmg);

    const int blocks = Btot / BB;                  // 2048
    wind_gemm_kernel<<<blocks, 512, 0, stream>>>(x, wmg, out);
}